// Round 10
// baseline (129.526 us; speedup 1.0000x reference)
//
#include <hip/hip_runtime.h>
#include <hip/hip_bf16.h>

#define B_ 4
#define N_ 4096
#define D_ 128
#define EPB (N_ * D_)        // BYTES per batch in packed fp8 layout = 524288

typedef float f32x4 __attribute__((ext_vector_type(4)));
typedef int   int8v __attribute__((ext_vector_type(8)));
typedef int   int4v __attribute__((ext_vector_type(4)));

#define SQRT2 1.41421356237309515f

// ---------------------------------------------------------------------------
// Packed K-major fp8 layout (per batch, BYTE addresses):
//   elem(row, k) -> (row>>4)*2048 + (k>>5)*512 + (row&15)*32 + (k&31)
// K=128 MFMA fragment (16x16x128 f8f6f4): lane (quad,l16): row = l16,
// k = quad*32 + j  ->  32 CONTIGUOUS bytes at rg*2048 + quad*512 + l16*32.
// REGISTER CLIFF LOG:
//   R13: computed-value acc init -> spill. RULE: acc inline-ZERO init only.
//   R15: rotation + full-unroll s-loop -> spill (liveness blowup).
// THEORY LEDGER (chamfer ~30us by subtraction vs ~5-7us issue floor):
//   occupancy NOT binding (R14 2x blocks worse; R16 more waves flat;
//     R19 1 fat block/CU flat).
//   load latency NOT binding (R17 depth-1 reg dbuf flat).
//   atomics NOT binding (R18 plain-store partials flat).
//   R20 hypothesis: the per-substep __shfl_xor chains. Shuffles are
//   ds_swizzle -> s_waitcnt lgkmcnt; 16 dependent ~120cyc hops/wave of
//   exposed latency, AND if any prefetch load is flat-class (flat bumps
//   lgkmcnt too) each shuffle wait drains the B-prefetch -- which would
//   explain R17's null. FIX: shuffle-free steady state. Each lane stores
//   its private 16-row col-min to a QUAD-indexed cpart slice (256 slices
//   per batch, 16MB total; ws >= 256MB per fill WRITE_SIZE). K-loop now
//   contains ONLY global loads + MFMA + VALU: zero lgkmcnt consumers.
//   finalize1 col-reduce widens 64->256 slices (coalesced, ~+1-2us).
// ---------------------------------------------------------------------------

// Kernel 1: fp32 -> fp8 e4m3 (*sqrt2) into packed layout + row norms.
__global__ __launch_bounds__(256) void prep_kernel(
    const float* __restrict__ X, const float* __restrict__ Y,
    unsigned char* __restrict__ Xb, unsigned char* __restrict__ Yb,
    float* __restrict__ x2, float* __restrict__ y2)
{
    const int which = blockIdx.y;
    const float* __restrict__ src = which ? Y : X;
    unsigned char* __restrict__ dst = which ? Yb : Xb;
    float* __restrict__ nrm = which ? y2 : x2;

    const int t = threadIdx.x;
    const int r = t >> 4, c = t & 15;          // r,c in 0..15
    const int rgG = blockIdx.x;                // global row-group
    const int row = rgG * 16 + r;

    const float4 v0 = *(const float4*)(src + (size_t)row * D_ + c * 8);
    const float4 v1 = *(const float4*)(src + (size_t)row * D_ + c * 8 + 4);

    float sq = v0.x * v0.x;
    sq = fmaf(v0.y, v0.y, sq); sq = fmaf(v0.z, v0.z, sq); sq = fmaf(v0.w, v0.w, sq);
    sq = fmaf(v1.x, v1.x, sq); sq = fmaf(v1.y, v1.y, sq);
    sq = fmaf(v1.z, v1.z, sq); sq = fmaf(v1.w, v1.w, sq);
    #pragma unroll
    for (int m = 1; m < 16; m <<= 1) sq += __shfl_xor(sq, m);

    unsigned lo = 0, hi = 0;
    lo = __builtin_amdgcn_cvt_pk_fp8_f32(v0.x * SQRT2, v0.y * SQRT2, lo, false);
    lo = __builtin_amdgcn_cvt_pk_fp8_f32(v0.z * SQRT2, v0.w * SQRT2, lo, true);
    hi = __builtin_amdgcn_cvt_pk_fp8_f32(v1.x * SQRT2, v1.y * SQRT2, hi, false);
    hi = __builtin_amdgcn_cvt_pk_fp8_f32(v1.z * SQRT2, v1.w * SQRT2, hi, true);

    const int b = row >> 12;
    const int rg = (row & (N_ - 1)) >> 4;
    uint2 packed; packed.x = lo; packed.y = hi;
    *(uint2*)(dst + (size_t)b * EPB + rg * 2048 + (c >> 2) * 512
              + r * 32 + (c & 3) * 8) = packed;

    if (c == 0) nrm[row] = sq;
}

// ---------------------------------------------------------------------------
// Kernel 2: stripe-sweep MX-fp8 (K=128) MFMA chamfer. NO LDS, NO barriers,
// NO atomics, NO in-loop shuffles. Block = 4 waves x 64 rows (grid y=16);
// jc = 256-col chunk (grid x=16); 8 substeps x 32 cols, depth-1 reg dbuf.
// acc ZERO-INIT only (AGPR rule). Fold:
//   rm = min(rm, y2 - acc);  cm(lane-private, 16 rows) = min(cm, x2 - acc)
//   -> stored per (wave,quad) slice; combined in finalize1.
//   C/D layout: row = quad*4 + reg, col = l16   [m89; shape-determined]
// ---------------------------------------------------------------------------

// prefetch substep H's 2 B-fragments + 2 y2 values into named regs
#define PREF(B0, B1, Y0, Y1, H) do {                                          \
    const int cb_ = jc * 256 + (H) * 32;                                      \
    const unsigned char* bp0_ = Yp + (size_t)(cb_ >> 4) * 2048                \
                               + quad * 512 + l16 * 32;                       \
    const int4v lo0_ = *(const int4v*)(bp0_);                                 \
    const int4v hi0_ = *(const int4v*)(bp0_ + 16);                            \
    const int4v lo1_ = *(const int4v*)(bp0_ + 2048);                          \
    const int4v hi1_ = *(const int4v*)(bp0_ + 2064);                          \
    B0 = (int8v){lo0_.x, lo0_.y, lo0_.z, lo0_.w, hi0_.x, hi0_.y, hi0_.z, hi0_.w}; \
    B1 = (int8v){lo1_.x, lo1_.y, lo1_.z, lo1_.w, hi1_.x, hi1_.y, hi1_.z, hi1_.w}; \
    Y0 = y2[(size_t)b * N_ + cb_ + l16];                                      \
    Y1 = y2[(size_t)b * N_ + cb_ + 16 + l16];                                 \
} while (0)

// 8 MFMAs + fold for substep H; lane-private col-min stored per quad slice
#define STEP(B0, B1, Y0, Y1, H) do {                                          \
    f32x4 acc0_[4], acc1_[4];                                                 \
    _Pragma("unroll")                                                         \
    for (int rt = 0; rt < 4; rt++) {                                          \
        acc0_[rt] = (f32x4){0.f, 0.f, 0.f, 0.f};                              \
        acc1_[rt] = (f32x4){0.f, 0.f, 0.f, 0.f};                              \
    }                                                                         \
    _Pragma("unroll")                                                         \
    for (int rt = 0; rt < 4; rt++) {                                          \
        acc0_[rt] = __builtin_amdgcn_mfma_scale_f32_16x16x128_f8f6f4(         \
            af[rt], B0, acc0_[rt], 0, 0, 0, 127, 0, 127);                     \
        acc1_[rt] = __builtin_amdgcn_mfma_scale_f32_16x16x128_f8f6f4(         \
            af[rt], B1, acc1_[rt], 0, 0, 0, 127, 0, 127);                     \
    }                                                                         \
    float cm0_ = 3.0e38f, cm1_ = 3.0e38f;                                     \
    _Pragma("unroll")                                                         \
    for (int rt = 0; rt < 4; rt++)                                            \
    _Pragma("unroll")                                                         \
    for (int i = 0; i < 4; i++) {                                             \
        const float xv_ = x2v[rt][i];                                         \
        const float a0_ = acc0_[rt][i], a1_ = acc1_[rt][i];                   \
        rmin[rt][i] = fminf(rmin[rt][i], fminf(Y0 - a0_, Y1 - a1_));          \
        cm0_ = fminf(cm0_, xv_ - a0_);                                        \
        cm1_ = fminf(cm1_, xv_ - a1_);                                        \
    }                                                                         \
    {                                                                         \
        const int cb_ = jc * 256 + (H) * 32;                                  \
        cpart[cpb + cb_ + l16] = cm0_;                                        \
        cpart[cpb + cb_ + 16 + l16] = cm1_;                                   \
    }                                                                         \
} while (0)

__global__ __launch_bounds__(256, 2) void chamfer_mfma(
    const unsigned char* __restrict__ Xb, const unsigned char* __restrict__ Yb,
    const float* __restrict__ x2, const float* __restrict__ y2,
    float* __restrict__ rpart, float* __restrict__ cpart)
{
    const int b = blockIdx.z;
    const int iT = blockIdx.y;           // 0..15  (256-row stripe)
    const int jc = blockIdx.x;           // 0..15  (256-col chunk)
    const int tid = threadIdx.x;
    const int wave = tid >> 6, lane = tid & 63;
    const int quad = lane >> 4, l16 = lane & 15;
    const int rowBase = iT * 256 + wave * 64;
    // unique-writer partial bases (cpart now per (iT,wave,quad): 256/batch)
    const size_t cpb = (size_t)(((b * 16 + iT) * 4 + wave) * 4 + quad) * N_;
    const size_t rpb = (size_t)(b * 16 + jc) * N_;

    const unsigned char* __restrict__ Xp = Xb + (size_t)b * EPB;
    const unsigned char* __restrict__ Yp = Yb + (size_t)b * EPB;

    // ---- A fragments resident (4 x v8i32 = 32 VGPR), register-only build ----
    int8v af[4];
    #pragma unroll
    for (int rt = 0; rt < 4; rt++) {
        const unsigned char* ap = Xp + ((rowBase >> 4) + rt) * 2048
                                 + quad * 512 + l16 * 32;
        const int4v lo = *(const int4v*)(ap);
        const int4v hi = *(const int4v*)(ap + 16);
        af[rt] = (int8v){lo.x, lo.y, lo.z, lo.w, hi.x, hi.y, hi.z, hi.w};
    }
    // row = rowBase + rt*16 + quad*4 + i -> one aligned float4 per rt
    f32x4 x2v[4];
    #pragma unroll
    for (int rt = 0; rt < 4; rt++)
        x2v[rt] = *(const f32x4*)(x2 + (size_t)b * N_ + rowBase + rt * 16 + quad * 4);

    float rmin[4][4];
    #pragma unroll
    for (int rt = 0; rt < 4; rt++)
        #pragma unroll
        for (int i = 0; i < 4; i++) rmin[rt][i] = 3.0e38f;

    // ---- depth-1 double-buffered substep pipeline (8 substeps) ----
    int8v bA0, bA1, bB0, bB1;
    float yA0, yA1, yB0, yB1;
    PREF(bA0, bA1, yA0, yA1, 0);

    #pragma clang loop unroll(disable)
    for (int sp = 0; sp < 4; ++sp) {
        const int h0 = sp * 2;
        PREF(bB0, bB1, yB0, yB1, h0 + 1);   // lands under STEP(h0)
        STEP(bA0, bA1, yA0, yA1, h0);
        if (sp < 3)
            PREF(bA0, bA1, yA0, yA1, h0 + 2);  // lands under STEP(h0+1)
        STEP(bB0, bB1, yB0, yB1, h0 + 1);
    }

    // ---- rowmin partial emission (once per block; shuffles OK here) ----
    #pragma unroll
    for (int rt = 0; rt < 4; rt++)
        #pragma unroll
        for (int i = 0; i < 4; i++) {
            float v = rmin[rt][i];
            #pragma unroll
            for (int m = 1; m < 16; m <<= 1) v = fminf(v, __shfl_xor(v, m));
            if (l16 == 0) {
                // clamp commutes with the later min over jc (monotone)
                rpart[rpb + rowBase + rt * 16 + quad * 4 + i] =
                    fminf(fmaxf(x2v[rt][i] + v, 0.0f), 100.0f);
            }
        }
}

// ---------------------------------------------------------------------------
// Kernel 3a: reduce partials. 64 blocks x 256 threads; element e = thread.
//   rowmin: min over 16 jc slices of rpart (already clamped).
//   colmin: min over 256 (iT,wave,quad) slices of cpart, + y2, clamp.
// All reads coalesced (consecutive threads -> consecutive elements/slice).
// ---------------------------------------------------------------------------
__global__ __launch_bounds__(256) void finalize1_kernel(
    const float* __restrict__ rpart, const float* __restrict__ cpart,
    const float* __restrict__ y2, float* __restrict__ partial)
{
    const int e = blockIdx.x * 256 + threadIdx.x;   // 0..16383
    const int b = e >> 12, i = e & (N_ - 1);

    float rm = 3.0e38f;
    #pragma unroll
    for (int j = 0; j < 16; j++)
        rm = fminf(rm, rpart[(size_t)(b * 16 + j) * N_ + i]);

    float cm = 3.0e38f;
    #pragma unroll 8
    for (int p = 0; p < 256; p++)
        cm = fminf(cm, cpart[(size_t)(b * 256 + p) * N_ + i]);

    float s = rm + fminf(fmaxf(cm + y2[e], 0.0f), 100.0f);

    #pragma unroll
    for (int m = 1; m < 64; m <<= 1) s += __shfl_xor(s, m);
    __shared__ float sm[4];
    if ((threadIdx.x & 63) == 0) sm[threadIdx.x >> 6] = s;
    __syncthreads();
    if (threadIdx.x == 0)
        partial[blockIdx.x] = sm[0] + sm[1] + sm[2] + sm[3];
}

// Kernel 3b: one wave folds the 64 partials.
__global__ __launch_bounds__(64) void finalize2_kernel(
    const float* __restrict__ partial, float* __restrict__ out)
{
    const int l = threadIdx.x;
    float s = partial[l];
    #pragma unroll
    for (int m = 1; m < 64; m <<= 1) s += __shfl_xor(s, m);
    if (l == 0)
        out[0] = s / ((float)B_ * (float)N_) / (float)B_;
}

extern "C" void kernel_launch(void* const* d_in, const int* in_sizes, int n_in,
                              void* d_out, int out_size, void* d_ws, size_t ws_size,
                              hipStream_t stream) {
    const float* X = (const float*)d_in[0];   // corr_pred   [B,N,D] fp32
    const float* Y = (const float*)d_in[1];   // corr_target [B,N,D] fp32

    char* ws = (char*)d_ws;
    const size_t f8_bytes = (size_t)B_ * N_ * D_;       // 2 MB each (packed fp8)
    unsigned char* Xb = (unsigned char*)ws;
    unsigned char* Yb = (unsigned char*)(ws + f8_bytes);
    char* ws2 = ws + 2 * f8_bytes;
    const size_t vec_bytes = (size_t)B_ * N_ * 4;       // 64 KB each
    float* x2      = (float*)(ws2);
    float* y2      = (float*)(ws2 + vec_bytes);
    float* rpart   = (float*)(ws2 + 2 * vec_bytes);               // 1 MB
    float* cpart   = (float*)(ws2 + 18 * vec_bytes);              // 16 MB
    float* partial = (float*)(ws2 + 274 * vec_bytes);             // 64 floats
    float* out = (float*)d_out;

    prep_kernel<<<dim3(B_ * N_ / 16, 2), 256, 0, stream>>>(
        X, Y, Xb, Yb, x2, y2);
    chamfer_mfma<<<dim3(16, 16, B_), 256, 0, stream>>>(
        Xb, Yb, x2, y2, rpart, cpart);
    finalize1_kernel<<<64, 256, 0, stream>>>(rpart, cpart, y2, partial);
    finalize2_kernel<<<1, 64, 0, stream>>>(partial, out);
}

// Round 11
// 90.072 us; speedup vs baseline: 1.4380x; 1.4380x over previous
//
#include <hip/hip_runtime.h>
#include <hip/hip_bf16.h>

#define B_ 4
#define N_ 4096
#define D_ 128
#define EPB (N_ * D_)        // BYTES per batch in packed fp8 layout = 524288

typedef float f32x4 __attribute__((ext_vector_type(4)));
typedef int   int8v __attribute__((ext_vector_type(8)));
typedef int   int4v __attribute__((ext_vector_type(4)));

#define SQRT2 1.41421356237309515f

// ---------------------------------------------------------------------------
// Packed K-major fp8 layout (per batch, BYTE addresses):
//   elem(row, k) -> (row>>4)*2048 + (k>>5)*512 + (row&15)*32 + (k&31)
// K=128 MFMA fragment (16x16x128 f8f6f4): lane (quad,l16): row = l16,
// k = quad*32 + j  ->  32 CONTIGUOUS bytes at rg*2048 + quad*512 + l16*32.
// REGISTER CLIFF LOG:
//   R13: computed-value acc init -> spill. RULE: acc inline-ZERO init only.
//   R15: rotation + full-unroll s-loop -> spill (liveness blowup).
// THEORY LEDGER:
//   chamfer structural theories all null: occupancy (R14/R16/R19),
//   load latency (R17), atomics (R18), in-loop shuffles (R20).
//   R20 FOUND THE HIDDEN COST: 64-block finalize reduce is latency-bound
//   (measured 45us @ 272 loads/thread, 200 GB/s, 2.3% occupancy). Scaling
//   to R18's 81 loads/thread => R18 finalize1 was ~10-13us, NOT 3-5.
//   => chamfer ~25us, finalize the 2nd-biggest controllable cost.
// R21: R18 chamfer byte-identical (known-clean). finalize1 reworked:
//   256 blocks x 256 threads, thread=(elem-of-64, slicegroup-of-4),
//   21 loads/thread, LDS combine across groups. Predict fin1 ~3us.
// ---------------------------------------------------------------------------

// Kernel 1: fp32 -> fp8 e4m3 (*sqrt2) into packed layout + row norms.
__global__ __launch_bounds__(256) void prep_kernel(
    const float* __restrict__ X, const float* __restrict__ Y,
    unsigned char* __restrict__ Xb, unsigned char* __restrict__ Yb,
    float* __restrict__ x2, float* __restrict__ y2)
{
    const int which = blockIdx.y;
    const float* __restrict__ src = which ? Y : X;
    unsigned char* __restrict__ dst = which ? Yb : Xb;
    float* __restrict__ nrm = which ? y2 : x2;

    const int t = threadIdx.x;
    const int r = t >> 4, c = t & 15;          // r,c in 0..15
    const int rgG = blockIdx.x;                // global row-group
    const int row = rgG * 16 + r;

    const float4 v0 = *(const float4*)(src + (size_t)row * D_ + c * 8);
    const float4 v1 = *(const float4*)(src + (size_t)row * D_ + c * 8 + 4);

    float sq = v0.x * v0.x;
    sq = fmaf(v0.y, v0.y, sq); sq = fmaf(v0.z, v0.z, sq); sq = fmaf(v0.w, v0.w, sq);
    sq = fmaf(v1.x, v1.x, sq); sq = fmaf(v1.y, v1.y, sq);
    sq = fmaf(v1.z, v1.z, sq); sq = fmaf(v1.w, v1.w, sq);
    #pragma unroll
    for (int m = 1; m < 16; m <<= 1) sq += __shfl_xor(sq, m);

    unsigned lo = 0, hi = 0;
    lo = __builtin_amdgcn_cvt_pk_fp8_f32(v0.x * SQRT2, v0.y * SQRT2, lo, false);
    lo = __builtin_amdgcn_cvt_pk_fp8_f32(v0.z * SQRT2, v0.w * SQRT2, lo, true);
    hi = __builtin_amdgcn_cvt_pk_fp8_f32(v1.x * SQRT2, v1.y * SQRT2, hi, false);
    hi = __builtin_amdgcn_cvt_pk_fp8_f32(v1.z * SQRT2, v1.w * SQRT2, hi, true);

    const int b = row >> 12;
    const int rg = (row & (N_ - 1)) >> 4;
    uint2 packed; packed.x = lo; packed.y = hi;
    *(uint2*)(dst + (size_t)b * EPB + rg * 2048 + (c >> 2) * 512
              + r * 32 + (c & 3) * 8) = packed;

    if (c == 0) nrm[row] = sq;
}

// ---------------------------------------------------------------------------
// Kernel 2 (R18, byte-identical — best clean measured): stripe-sweep MX-fp8
// (K=128) MFMA chamfer. NO LDS, NO barriers, NO atomics. Block = 4 waves x
// 64 rows (grid y=16); jc = 256-col chunk (grid x=16); 8 substeps x 32 cols,
// depth-1 reg double-buffer. acc ZERO-INIT only (AGPR rule). Fold:
//   rm = min(rm, y2 - acc);  cm = min(cm, x2 - acc).
//   C/D layout: row = quad*4 + reg, col = l16   [m89; shape-determined]
// ---------------------------------------------------------------------------

// prefetch substep H's 2 B-fragments + 2 y2 values into named regs
#define PREF(B0, B1, Y0, Y1, H) do {                                          \
    const int cb_ = jc * 256 + (H) * 32;                                      \
    const unsigned char* bp0_ = Yp + (size_t)(cb_ >> 4) * 2048                \
                               + quad * 512 + l16 * 32;                       \
    const int4v lo0_ = *(const int4v*)(bp0_);                                 \
    const int4v hi0_ = *(const int4v*)(bp0_ + 16);                            \
    const int4v lo1_ = *(const int4v*)(bp0_ + 2048);                          \
    const int4v hi1_ = *(const int4v*)(bp0_ + 2064);                          \
    B0 = (int8v){lo0_.x, lo0_.y, lo0_.z, lo0_.w, hi0_.x, hi0_.y, hi0_.z, hi0_.w}; \
    B1 = (int8v){lo1_.x, lo1_.y, lo1_.z, lo1_.w, hi1_.x, hi1_.y, hi1_.z, hi1_.w}; \
    Y0 = y2[(size_t)b * N_ + cb_ + l16];                                      \
    Y1 = y2[(size_t)b * N_ + cb_ + 16 + l16];                                 \
} while (0)

// 8 MFMAs + fold for substep H using named buffers; col-min via plain store
#define STEP(B0, B1, Y0, Y1, H) do {                                          \
    f32x4 acc0_[4], acc1_[4];                                                 \
    _Pragma("unroll")                                                         \
    for (int rt = 0; rt < 4; rt++) {                                          \
        acc0_[rt] = (f32x4){0.f, 0.f, 0.f, 0.f};                              \
        acc1_[rt] = (f32x4){0.f, 0.f, 0.f, 0.f};                              \
    }                                                                         \
    _Pragma("unroll")                                                         \
    for (int rt = 0; rt < 4; rt++) {                                          \
        acc0_[rt] = __builtin_amdgcn_mfma_scale_f32_16x16x128_f8f6f4(         \
            af[rt], B0, acc0_[rt], 0, 0, 0, 127, 0, 127);                     \
        acc1_[rt] = __builtin_amdgcn_mfma_scale_f32_16x16x128_f8f6f4(         \
            af[rt], B1, acc1_[rt], 0, 0, 0, 127, 0, 127);                     \
    }                                                                         \
    float cm0_ = 3.0e38f, cm1_ = 3.0e38f;                                     \
    _Pragma("unroll")                                                         \
    for (int rt = 0; rt < 4; rt++)                                            \
    _Pragma("unroll")                                                         \
    for (int i = 0; i < 4; i++) {                                             \
        const float xv_ = x2v[rt][i];                                         \
        const float a0_ = acc0_[rt][i], a1_ = acc1_[rt][i];                   \
        rmin[rt][i] = fminf(rmin[rt][i], fminf(Y0 - a0_, Y1 - a1_));          \
        cm0_ = fminf(cm0_, xv_ - a0_);                                        \
        cm1_ = fminf(cm1_, xv_ - a1_);                                        \
    }                                                                         \
    {                                                                         \
        const int cb_ = jc * 256 + (H) * 32;                                  \
        float v0_ = fminf(cm0_, __shfl_xor(cm0_, 16));                        \
        v0_ = fminf(v0_, __shfl_xor(v0_, 32));                                \
        float v1_ = fminf(cm1_, __shfl_xor(cm1_, 16));                        \
        v1_ = fminf(v1_, __shfl_xor(v1_, 32));                                \
        if (quad == 0) {                                                      \
            cpart[cpb + cb_ + l16] = v0_;                                     \
            cpart[cpb + cb_ + 16 + l16] = v1_;                                \
        }                                                                     \
    }                                                                         \
} while (0)

__global__ __launch_bounds__(256, 2) void chamfer_mfma(
    const unsigned char* __restrict__ Xb, const unsigned char* __restrict__ Yb,
    const float* __restrict__ x2, const float* __restrict__ y2,
    float* __restrict__ rpart, float* __restrict__ cpart)
{
    const int b = blockIdx.z;
    const int iT = blockIdx.y;           // 0..15  (256-row stripe)
    const int jc = blockIdx.x;           // 0..15  (256-col chunk)
    const int tid = threadIdx.x;
    const int wave = tid >> 6, lane = tid & 63;
    const int quad = lane >> 4, l16 = lane & 15;
    const int rowBase = iT * 256 + wave * 64;
    // unique-writer partial bases
    const size_t cpb = (size_t)((b * 16 + iT) * 4 + wave) * N_;
    const size_t rpb = (size_t)(b * 16 + jc) * N_;

    const unsigned char* __restrict__ Xp = Xb + (size_t)b * EPB;
    const unsigned char* __restrict__ Yp = Yb + (size_t)b * EPB;

    // ---- A fragments resident (4 x v8i32 = 32 VGPR), register-only build ----
    int8v af[4];
    #pragma unroll
    for (int rt = 0; rt < 4; rt++) {
        const unsigned char* ap = Xp + ((rowBase >> 4) + rt) * 2048
                                 + quad * 512 + l16 * 32;
        const int4v lo = *(const int4v*)(ap);
        const int4v hi = *(const int4v*)(ap + 16);
        af[rt] = (int8v){lo.x, lo.y, lo.z, lo.w, hi.x, hi.y, hi.z, hi.w};
    }
    // row = rowBase + rt*16 + quad*4 + i -> one aligned float4 per rt
    f32x4 x2v[4];
    #pragma unroll
    for (int rt = 0; rt < 4; rt++)
        x2v[rt] = *(const f32x4*)(x2 + (size_t)b * N_ + rowBase + rt * 16 + quad * 4);

    float rmin[4][4];
    #pragma unroll
    for (int rt = 0; rt < 4; rt++)
        #pragma unroll
        for (int i = 0; i < 4; i++) rmin[rt][i] = 3.0e38f;

    // ---- depth-1 double-buffered substep pipeline (8 substeps) ----
    int8v bA0, bA1, bB0, bB1;
    float yA0, yA1, yB0, yB1;
    PREF(bA0, bA1, yA0, yA1, 0);

    #pragma clang loop unroll(disable)
    for (int sp = 0; sp < 4; ++sp) {
        const int h0 = sp * 2;
        PREF(bB0, bB1, yB0, yB1, h0 + 1);   // lands under STEP(h0)
        STEP(bA0, bA1, yA0, yA1, h0);
        if (sp < 3)
            PREF(bA0, bA1, yA0, yA1, h0 + 2);  // lands under STEP(h0+1)
        STEP(bB0, bB1, yB0, yB1, h0 + 1);
    }

    // ---- rowmin partial emission (once per block; plain stores) ----
    #pragma unroll
    for (int rt = 0; rt < 4; rt++)
        #pragma unroll
        for (int i = 0; i < 4; i++) {
            float v = rmin[rt][i];
            #pragma unroll
            for (int m = 1; m < 16; m <<= 1) v = fminf(v, __shfl_xor(v, m));
            if (l16 == 0) {
                // clamp commutes with the later min over jc (monotone)
                rpart[rpb + rowBase + rt * 16 + quad * 4 + i] =
                    fminf(fmaxf(x2v[rt][i] + v, 0.0f), 100.0f);
            }
        }
}

// ---------------------------------------------------------------------------
// Kernel 3a (R21 rework): parallel partial-reduce.
// 256 blocks x 256 threads. Thread = (e_loc = tid&63, sg = tid>>6).
// Each thread reduces 4 rpart slices + 16 cpart slices for its element
// (21 loads, all coalesced: a wave covers 64 consecutive elements of one
// slice group). LDS combine across the 4 slice groups, then wave 0
// computes s and block-sums -> partial[256].
// ---------------------------------------------------------------------------
__global__ __launch_bounds__(256) void finalize1_kernel(
    const float* __restrict__ rpart, const float* __restrict__ cpart,
    const float* __restrict__ y2, float* __restrict__ partial)
{
    const int e_loc = threadIdx.x & 63, sg = threadIdx.x >> 6;  // sg 0..3
    const int e = blockIdx.x * 64 + e_loc;                      // 0..16383
    const int b = e >> 12, i = e & (N_ - 1);

    float rm = 3.0e38f;
    #pragma unroll
    for (int j = 0; j < 4; j++)
        rm = fminf(rm, rpart[(size_t)(b * 16 + sg * 4 + j) * N_ + i]);

    float cm = 3.0e38f;
    #pragma unroll
    for (int p = 0; p < 16; p++)
        cm = fminf(cm, cpart[(size_t)(b * 64 + sg * 16 + p) * N_ + i]);

    __shared__ float smr[4][64], smc[4][64];
    smr[sg][e_loc] = rm;
    smc[sg][e_loc] = cm;
    __syncthreads();

    if (sg == 0) {
        rm = fminf(fminf(smr[0][e_loc], smr[1][e_loc]),
                   fminf(smr[2][e_loc], smr[3][e_loc]));
        cm = fminf(fminf(smc[0][e_loc], smc[1][e_loc]),
                   fminf(smc[2][e_loc], smc[3][e_loc]));
        float s = rm + fminf(fmaxf(cm + y2[e], 0.0f), 100.0f);
        #pragma unroll
        for (int m = 1; m < 64; m <<= 1) s += __shfl_xor(s, m);
        if (e_loc == 0) partial[blockIdx.x] = s;
    }
}

// Kernel 3b: one wave folds the 256 partials.
__global__ __launch_bounds__(64) void finalize2_kernel(
    const float* __restrict__ partial, float* __restrict__ out)
{
    const int l = threadIdx.x;
    float s = partial[l] + partial[l + 64] + partial[l + 128] + partial[l + 192];
    #pragma unroll
    for (int m = 1; m < 64; m <<= 1) s += __shfl_xor(s, m);
    if (l == 0)
        out[0] = s / ((float)B_ * (float)N_) / (float)B_;
}

extern "C" void kernel_launch(void* const* d_in, const int* in_sizes, int n_in,
                              void* d_out, int out_size, void* d_ws, size_t ws_size,
                              hipStream_t stream) {
    const float* X = (const float*)d_in[0];   // corr_pred   [B,N,D] fp32
    const float* Y = (const float*)d_in[1];   // corr_target [B,N,D] fp32

    char* ws = (char*)d_ws;
    const size_t f8_bytes = (size_t)B_ * N_ * D_;       // 2 MB each (packed fp8)
    unsigned char* Xb = (unsigned char*)ws;
    unsigned char* Yb = (unsigned char*)(ws + f8_bytes);
    char* ws2 = ws + 2 * f8_bytes;
    const size_t vec_bytes = (size_t)B_ * N_ * 4;       // 64 KB each
    float* x2      = (float*)(ws2);
    float* y2      = (float*)(ws2 + vec_bytes);
    float* rpart   = (float*)(ws2 + 2 * vec_bytes);               // 1 MB
    float* cpart   = (float*)(ws2 + 18 * vec_bytes);              // 4 MB
    float* partial = (float*)(ws2 + 82 * vec_bytes);              // 256 floats
    float* out = (float*)d_out;

    prep_kernel<<<dim3(B_ * N_ / 16, 2), 256, 0, stream>>>(
        X, Y, Xb, Yb, x2, y2);
    chamfer_mfma<<<dim3(16, 16, B_), 256, 0, stream>>>(
        Xb, Yb, x2, y2, rpart, cpart);
    finalize1_kernel<<<256, 256, 0, stream>>>(rpart, cpart, y2, partial);
    finalize2_kernel<<<1, 64, 0, stream>>>(partial, out);
}

// Round 12
// 88.688 us; speedup vs baseline: 1.4605x; 1.0156x over previous
//
#include <hip/hip_runtime.h>
#include <hip/hip_bf16.h>

#define B_ 4
#define N_ 4096
#define D_ 128
#define EPB (N_ * D_)        // BYTES per batch in packed fp8 layout = 524288

typedef float f32x4 __attribute__((ext_vector_type(4)));
typedef int   int8v __attribute__((ext_vector_type(8)));
typedef int   int4v __attribute__((ext_vector_type(4)));

#define SQRT2 1.41421356237309515f

// ---------------------------------------------------------------------------
// Packed K-major fp8 layout (per batch, BYTE addresses):
//   elem(row, k) -> (row>>4)*2048 + (k>>5)*512 + (row&15)*32 + (k&31)
// K=128 MFMA fragment (16x16x128 f8f6f4): lane (quad,l16): row = l16,
// k = quad*32 + j  ->  32 CONTIGUOUS bytes at rg*2048 + quad*512 + l16*32.
// REGISTER CLIFF LOG:
//   R13: computed-value acc init -> spill. RULE: acc inline-ZERO init only.
//   R15: rotation + full-unroll s-loop -> spill (liveness blowup).
// THEORY LEDGER: chamfer pinned ~28us across SEVEN variants: occupancy-
//   requested (R14/R16/R19), prefetch (R17), atomics->stores (R18),
//   shuffle-free (R20), finalize rework (R21). All ±2.5us.
// R22 insight: R16 only PERMITTED 3 waves/SIMD (launch_bounds floor);
//   allocator likely stayed ~190 regs -> 2 waves. FORCE it:
//   __launch_bounds__(256,3) caps unified regs at 170. Made feasible by:
//   - NO prefetch (R17 proved null; frees 16 VGPR, single bfv buffer)
//   - NO in-loop shuffles (quad-private cm -> 256-slice cpart; R20 proved
//     chamfer-neutral; removes lgkmcnt waits)
//   - tree/min3 folds.
//   Budget: af32+x2v16+rmin16+bfv16+misc~45 = ~125 arch + 32 AGPR = ~157.
// ---------------------------------------------------------------------------

// Kernel 1: fp32 -> fp8 e4m3 (*sqrt2) into packed layout + row norms.
__global__ __launch_bounds__(256) void prep_kernel(
    const float* __restrict__ X, const float* __restrict__ Y,
    unsigned char* __restrict__ Xb, unsigned char* __restrict__ Yb,
    float* __restrict__ x2, float* __restrict__ y2)
{
    const int which = blockIdx.y;
    const float* __restrict__ src = which ? Y : X;
    unsigned char* __restrict__ dst = which ? Yb : Xb;
    float* __restrict__ nrm = which ? y2 : x2;

    const int t = threadIdx.x;
    const int r = t >> 4, c = t & 15;          // r,c in 0..15
    const int rgG = blockIdx.x;                // global row-group
    const int row = rgG * 16 + r;

    const float4 v0 = *(const float4*)(src + (size_t)row * D_ + c * 8);
    const float4 v1 = *(const float4*)(src + (size_t)row * D_ + c * 8 + 4);

    float sq = v0.x * v0.x;
    sq = fmaf(v0.y, v0.y, sq); sq = fmaf(v0.z, v0.z, sq); sq = fmaf(v0.w, v0.w, sq);
    sq = fmaf(v1.x, v1.x, sq); sq = fmaf(v1.y, v1.y, sq);
    sq = fmaf(v1.z, v1.z, sq); sq = fmaf(v1.w, v1.w, sq);
    #pragma unroll
    for (int m = 1; m < 16; m <<= 1) sq += __shfl_xor(sq, m);

    unsigned lo = 0, hi = 0;
    lo = __builtin_amdgcn_cvt_pk_fp8_f32(v0.x * SQRT2, v0.y * SQRT2, lo, false);
    lo = __builtin_amdgcn_cvt_pk_fp8_f32(v0.z * SQRT2, v0.w * SQRT2, lo, true);
    hi = __builtin_amdgcn_cvt_pk_fp8_f32(v1.x * SQRT2, v1.y * SQRT2, hi, false);
    hi = __builtin_amdgcn_cvt_pk_fp8_f32(v1.z * SQRT2, v1.w * SQRT2, hi, true);

    const int b = row >> 12;
    const int rg = (row & (N_ - 1)) >> 4;
    uint2 packed; packed.x = lo; packed.y = hi;
    *(uint2*)(dst + (size_t)b * EPB + rg * 2048 + (c >> 2) * 512
              + r * 32 + (c & 3) * 8) = packed;

    if (c == 0) nrm[row] = sq;
}

// ---------------------------------------------------------------------------
// Kernel 2: stripe-sweep MX-fp8 (K=128) MFMA chamfer. NO LDS, NO barriers,
// NO atomics, NO in-loop shuffles, NO prefetch. Block = 4 waves x 64 rows
// (grid y=16); jc = 256-col chunk (grid x=16); 8 substeps x 32 cols.
// FORCED 3 waves/SIMD via __launch_bounds__(256,3). acc ZERO-INIT (AGPR
// rule). Fold: rm = min3(rm, y0-a0, y1-a1); cm tree-min per lane's 16 rows,
// stored per (iT,wave,quad) cpart slice (256 slices/batch).
//   C/D layout: row = quad*4 + reg, col = l16   [m89; shape-determined]
// ---------------------------------------------------------------------------
__global__ __launch_bounds__(256, 3) void chamfer_mfma(
    const unsigned char* __restrict__ Xb, const unsigned char* __restrict__ Yb,
    const float* __restrict__ x2, const float* __restrict__ y2,
    float* __restrict__ rpart, float* __restrict__ cpart)
{
    const int b = blockIdx.z;
    const int iT = blockIdx.y;           // 0..15  (256-row stripe)
    const int jc = blockIdx.x;           // 0..15  (256-col chunk)
    const int tid = threadIdx.x;
    const int wave = tid >> 6, lane = tid & 63;
    const int quad = lane >> 4, l16 = lane & 15;
    const int rowBase = iT * 256 + wave * 64;
    // unique-writer partial bases (cpart per (iT,wave,quad): 256/batch)
    const size_t cpb = (size_t)(((b * 16 + iT) * 4 + wave) * 4 + quad) * N_;
    const size_t rpb = (size_t)(b * 16 + jc) * N_;

    const unsigned char* __restrict__ Xp = Xb + (size_t)b * EPB;
    const unsigned char* __restrict__ Yp = Yb + (size_t)b * EPB;

    // ---- A fragments resident (4 x v8i32 = 32 VGPR), register-only build ----
    int8v af[4];
    #pragma unroll
    for (int rt = 0; rt < 4; rt++) {
        const unsigned char* ap = Xp + ((rowBase >> 4) + rt) * 2048
                                 + quad * 512 + l16 * 32;
        const int4v lo = *(const int4v*)(ap);
        const int4v hi = *(const int4v*)(ap + 16);
        af[rt] = (int8v){lo.x, lo.y, lo.z, lo.w, hi.x, hi.y, hi.z, hi.w};
    }
    // row = rowBase + rt*16 + quad*4 + i -> one aligned float4 per rt
    f32x4 x2v[4];
    #pragma unroll
    for (int rt = 0; rt < 4; rt++)
        x2v[rt] = *(const f32x4*)(x2 + (size_t)b * N_ + rowBase + rt * 16 + quad * 4);

    float rmin[4][4];
    #pragma unroll
    for (int rt = 0; rt < 4; rt++)
        #pragma unroll
        for (int i = 0; i < 4; i++) rmin[rt][i] = 3.0e38f;

    // ---- 8 substeps x 32 cols; single bfv buffer, loads at substep top ----
    #pragma clang loop unroll(disable)
    for (int h = 0; h < 8; ++h) {
        const int cb = jc * 256 + h * 32;
        const unsigned char* bp = Yp + (size_t)(cb >> 4) * 2048
                                 + quad * 512 + l16 * 32;
        const int4v lo0 = *(const int4v*)(bp);
        const int4v hi0 = *(const int4v*)(bp + 16);
        const int4v lo1 = *(const int4v*)(bp + 2048);
        const int4v hi1 = *(const int4v*)(bp + 2064);
        const int8v b0 = (int8v){lo0.x, lo0.y, lo0.z, lo0.w,
                                 hi0.x, hi0.y, hi0.z, hi0.w};
        const int8v b1 = (int8v){lo1.x, lo1.y, lo1.z, lo1.w,
                                 hi1.x, hi1.y, hi1.z, hi1.w};
        const float y0 = y2[(size_t)b * N_ + cb + l16];
        const float y1 = y2[(size_t)b * N_ + cb + 16 + l16];

        f32x4 acc0[4], acc1[4];
        #pragma unroll
        for (int rt = 0; rt < 4; rt++) {
            acc0[rt] = (f32x4){0.f, 0.f, 0.f, 0.f};
            acc1[rt] = (f32x4){0.f, 0.f, 0.f, 0.f};
        }
        #pragma unroll
        for (int rt = 0; rt < 4; rt++) {
            acc0[rt] = __builtin_amdgcn_mfma_scale_f32_16x16x128_f8f6f4(
                af[rt], b0, acc0[rt], 0, 0, 0, 127, 0, 127);
            acc1[rt] = __builtin_amdgcn_mfma_scale_f32_16x16x128_f8f6f4(
                af[rt], b1, acc1[rt], 0, 0, 0, 127, 0, 127);
        }

        // ---- fold (pure VALU, min3-fusable trees, no cross-lane) ----
        float cm0 = 3.0e38f, cm1 = 3.0e38f;
        #pragma unroll
        for (int rt = 0; rt < 4; rt++) {
            float d00 = x2v[rt][0] - acc0[rt][0], d01 = x2v[rt][1] - acc0[rt][1];
            float d02 = x2v[rt][2] - acc0[rt][2], d03 = x2v[rt][3] - acc0[rt][3];
            float d10 = x2v[rt][0] - acc1[rt][0], d11 = x2v[rt][1] - acc1[rt][1];
            float d12 = x2v[rt][2] - acc1[rt][2], d13 = x2v[rt][3] - acc1[rt][3];
            cm0 = fminf(cm0, fminf(fminf(d00, d01), fminf(d02, d03)));
            cm1 = fminf(cm1, fminf(fminf(d10, d11), fminf(d12, d13)));
            #pragma unroll
            for (int i = 0; i < 4; i++)
                rmin[rt][i] = fminf(rmin[rt][i],
                                    fminf(y0 - acc0[rt][i], y1 - acc1[rt][i]));
        }
        cpart[cpb + cb + l16] = cm0;
        cpart[cpb + cb + 16 + l16] = cm1;
    }

    // ---- rowmin partial emission (once per block; shuffles OK here) ----
    #pragma unroll
    for (int rt = 0; rt < 4; rt++)
        #pragma unroll
        for (int i = 0; i < 4; i++) {
            float v = rmin[rt][i];
            #pragma unroll
            for (int m = 1; m < 16; m <<= 1) v = fminf(v, __shfl_xor(v, m));
            if (l16 == 0) {
                // clamp commutes with the later min over jc (monotone)
                rpart[rpb + rowBase + rt * 16 + quad * 4 + i] =
                    fminf(fmaxf(x2v[rt][i] + v, 0.0f), 100.0f);
            }
        }
}

// ---------------------------------------------------------------------------
// Kernel 3a: parallel partial-reduce. 256 blocks x 512 threads.
// Thread = (e_loc = tid&63, sg = tid>>6, sg 0..7). Per element:
//   rm over 2 rpart slices/sg (16 total), cm over 32 cpart slices/sg
//   (256 total). 34 coalesced loads/thread. LDS combine across 8 groups.
// ---------------------------------------------------------------------------
__global__ __launch_bounds__(512) void finalize1_kernel(
    const float* __restrict__ rpart, const float* __restrict__ cpart,
    const float* __restrict__ y2, float* __restrict__ partial)
{
    const int e_loc = threadIdx.x & 63, sg = threadIdx.x >> 6;  // sg 0..7
    const int e = blockIdx.x * 64 + e_loc;                      // 0..16383
    const int b = e >> 12, i = e & (N_ - 1);

    float rm = 3.0e38f;
    #pragma unroll
    for (int j = 0; j < 2; j++)
        rm = fminf(rm, rpart[(size_t)(b * 16 + sg * 2 + j) * N_ + i]);

    float cm = 3.0e38f;
    #pragma unroll
    for (int p = 0; p < 32; p++)
        cm = fminf(cm, cpart[(size_t)(b * 256 + sg * 32 + p) * N_ + i]);

    __shared__ float smr[8][64], smc[8][64];
    smr[sg][e_loc] = rm;
    smc[sg][e_loc] = cm;
    __syncthreads();

    if (sg == 0) {
        rm = smr[0][e_loc]; cm = smc[0][e_loc];
        #pragma unroll
        for (int g = 1; g < 8; g++) {
            rm = fminf(rm, smr[g][e_loc]);
            cm = fminf(cm, smc[g][e_loc]);
        }
        float s = rm + fminf(fmaxf(cm + y2[e], 0.0f), 100.0f);
        #pragma unroll
        for (int m = 1; m < 64; m <<= 1) s += __shfl_xor(s, m);
        if (e_loc == 0) partial[blockIdx.x] = s;
    }
}

// Kernel 3b: one wave folds the 256 partials.
__global__ __launch_bounds__(64) void finalize2_kernel(
    const float* __restrict__ partial, float* __restrict__ out)
{
    const int l = threadIdx.x;
    float s = partial[l] + partial[l + 64] + partial[l + 128] + partial[l + 192];
    #pragma unroll
    for (int m = 1; m < 64; m <<= 1) s += __shfl_xor(s, m);
    if (l == 0)
        out[0] = s / ((float)B_ * (float)N_) / (float)B_;
}

extern "C" void kernel_launch(void* const* d_in, const int* in_sizes, int n_in,
                              void* d_out, int out_size, void* d_ws, size_t ws_size,
                              hipStream_t stream) {
    const float* X = (const float*)d_in[0];   // corr_pred   [B,N,D] fp32
    const float* Y = (const float*)d_in[1];   // corr_target [B,N,D] fp32

    char* ws = (char*)d_ws;
    const size_t f8_bytes = (size_t)B_ * N_ * D_;       // 2 MB each (packed fp8)
    unsigned char* Xb = (unsigned char*)ws;
    unsigned char* Yb = (unsigned char*)(ws + f8_bytes);
    char* ws2 = ws + 2 * f8_bytes;
    const size_t vec_bytes = (size_t)B_ * N_ * 4;       // 64 KB each
    float* x2      = (float*)(ws2);
    float* y2      = (float*)(ws2 + vec_bytes);
    float* rpart   = (float*)(ws2 + 2 * vec_bytes);               // 1 MB
    float* cpart   = (float*)(ws2 + 18 * vec_bytes);              // 16 MB
    float* partial = (float*)(ws2 + 274 * vec_bytes);             // 256 floats
    float* out = (float*)d_out;

    prep_kernel<<<dim3(B_ * N_ / 16, 2), 256, 0, stream>>>(
        X, Y, Xb, Yb, x2, y2);
    chamfer_mfma<<<dim3(16, 16, B_), 256, 0, stream>>>(
        Xb, Yb, x2, y2, rpart, cpart);
    finalize1_kernel<<<256, 512, 0, stream>>>(rpart, cpart, y2, partial);
    finalize2_kernel<<<1, 64, 0, stream>>>(partial, out);
}